// Round 6
// baseline (940.785 us; speedup 1.0000x reference)
//
#include <hip/hip_runtime.h>

#define SPATIAL 32768
#define BATCH   4
#define CH      256
#define KCODES  1024
#define NPTS    (BATCH*SPATIAL)          // 131072
#define ZQ_SIZE (BATCH*CH*SPATIAL)       // 33554432

// workspace layout (bytes)
#define WS_LOSS  0                        // double
#define WS_CNT   8                        // int
#define WS_ENORM 16                       // float[1024]
#define WS_EH    4352                     // _Float16[1024*256] row-major
#define WS_EL    (WS_EH + KCODES*CH*2)
#define WS_FLAGS (WS_EL + KCODES*CH*2)    // int[NPTS]

#define MARG 1.5e-4f  // covers split err + MFMA-vs-chain diff + 2 ulp(512)

typedef _Float16 f16x8 __attribute__((ext_vector_type(8)));
typedef float    f32x4 __attribute__((ext_vector_type(4)));

// split e*1024 into f16 hi/lo, row-major (L2-friendly scattered reads in main)
__global__ __launch_bounds__(256) void vq_prep(const float* __restrict__ emb,
                                               _Float16* __restrict__ eh,
                                               _Float16* __restrict__ el) {
  int i = blockIdx.x * 256 + threadIdx.x;
  float es = emb[i] * 1024.0f;
  _Float16 h = (_Float16)es;
  eh[i] = h;
  el[i] = (_Float16)(es - (float)h);
}

__global__ __launch_bounds__(256) void vq_enorm(const float* __restrict__ emb,
                                                float* __restrict__ enorm) {
  int k = blockIdx.x * 256 + threadIdx.x;
  const float* e = emb + (size_t)k * CH;
  double s = 0.0;
#pragma unroll 8
  for (int c = 0; c < CH; ++c) s = fma((double)e[c], (double)e[c], s);
  enorm[k] = (float)s;
}

// 2048 blocks x 256 thr; block = 64 points x all 1024 codes, f16-split MFMA.
// Per wave per k-tile: 4 m-subtiles x 4 n-subtiles -> 48 MFMA per cc-step
// vs 8 ds_read_b128 (conflict-free zfrag layout) -> MFMA-pipe-bound.
__global__ __launch_bounds__(256, 2) void vq_main(
    const float* __restrict__ z, const _Float16* __restrict__ eh_g,
    const _Float16* __restrict__ el_g, const float* __restrict__ enorm,
    float* __restrict__ out_idx, double* __restrict__ loss_acc,
    int* __restrict__ flag_cnt, int* __restrict__ flags) {
  __shared__ f16x8 zfrag[64][64];   // [h*32 + m*8 + cc][lane]  = 64 KB
  __shared__ double znp[4][64];
  __shared__ float  znb[64];
  __shared__ float rm1s[4][64];
  __shared__ float rm2s[4][64];
  __shared__ int   ri1s[4][64];

  int tid = threadIdx.x;
  int w = tid >> 6;
  int lane = tid & 63;
  int n0 = blockIdx.x * 64;
  int b = n0 / SPATIAL, s0 = n0 % SPATIAL;
  const float* zb = z + (size_t)b * CH * SPATIAL + s0;

  // stage z as f16 hi/lo directly into fragment order; f64 zn partials
  {
    int pt = lane, m = pt >> 4, lr = pt & 15;
    const float* zcol = zb + pt;
    double zacc = 0.0;
#pragma unroll
    for (int oct = 0; oct < 8; ++oct) {
      int c0 = w * 64 + oct * 8;
      int cc = c0 >> 5, hq = (c0 >> 3) & 3;
      f16x8 h8, l8;
#pragma unroll
      for (int i = 0; i < 8; ++i) {
        float v = zcol[(size_t)(c0 + i) * SPATIAL];
        zacc = fma((double)v, (double)v, zacc);
        _Float16 hh = (_Float16)v;
        h8[i] = hh;
        l8[i] = (_Float16)(v - (float)hh);
      }
      zfrag[m * 8 + cc][hq * 16 + lr] = h8;
      zfrag[32 + m * 8 + cc][hq * 16 + lr] = l8;
    }
    znp[w][pt] = zacc;
  }
  __syncthreads();
  if (tid < 64)
    znb[tid] = (float)(znp[0][tid] + znp[1][tid] + znp[2][tid] + znp[3][tid]);
  __syncthreads();

  int hq = lane >> 4;
  int lr = lane & 15;

  // enorm fully in registers: [kt*4 + n]
  float en_reg[16];
#pragma unroll
  for (int kt = 0; kt < 4; ++kt)
#pragma unroll
    for (int n = 0; n < 4; ++n)
      en_reg[kt * 4 + n] = enorm[kt * 256 + w * 64 + n * 16 + lr];

  float znr[16];
#pragma unroll
  for (int m = 0; m < 4; ++m)
#pragma unroll
    for (int r = 0; r < 4; ++r) znr[m * 4 + r] = znb[m * 16 + hq * 4 + r];

  float rm1[16], rm2[16];
  int   ri1[16];
#pragma unroll
  for (int q = 0; q < 16; ++q) { rm1[q] = 1e30f; rm2[q] = 1e30f; ri1[q] = 0; }

  // row bases for this wave's 4 code-subtiles (row-major e, L2-resident)
  const _Float16* ehb = eh_g + (size_t)(w * 64 + lr) * CH;
  const _Float16* elb = el_g + (size_t)(w * 64 + lr) * CH;

  for (int kt = 0; kt < 4; ++kt) {
    size_t ktoff = (size_t)kt * 256 * CH;
    f32x4 acc[4][4];
#pragma unroll
    for (int m = 0; m < 4; ++m)
#pragma unroll
      for (int n = 0; n < 4; ++n) acc[m][n] = (f32x4){0.f, 0.f, 0.f, 0.f};

#pragma unroll
    for (int cc = 0; cc < 8; ++cc) {
      int ca = cc * 32 + hq * 8;
      f16x8 bh[4], bl[4];
#pragma unroll
      for (int n = 0; n < 4; ++n) {
        size_t off = ktoff + (size_t)(n * 16) * CH + ca;
        bh[n] = *(const f16x8*)&ehb[off];
        bl[n] = *(const f16x8*)&elb[off];
      }
      f16x8 ah[4], al[4];
#pragma unroll
      for (int m = 0; m < 4; ++m) {
        ah[m] = zfrag[m * 8 + cc][lane];
        al[m] = zfrag[32 + m * 8 + cc][lane];
      }
#pragma unroll
      for (int m = 0; m < 4; ++m)
#pragma unroll
        for (int n = 0; n < 4; ++n) {
          acc[m][n] = __builtin_amdgcn_mfma_f32_16x16x32_f16(ah[m], bh[n], acc[m][n], 0, 0, 0);
          acc[m][n] = __builtin_amdgcn_mfma_f32_16x16x32_f16(al[m], bh[n], acc[m][n], 0, 0, 0);
          acc[m][n] = __builtin_amdgcn_mfma_f32_16x16x32_f16(ah[m], bl[n], acc[m][n], 0, 0, 0);
        }
    }

    // fold into per-thread top-2 (D-frag: row = hq*4+r, col = lr)
    int c0i = kt * 256 + w * 64 + lr;
#pragma unroll
    for (int m = 0; m < 4; ++m) {
#pragma unroll
      for (int r = 0; r < 4; ++r) {
        int q = m * 4 + r;
        float zn = znr[q];
#pragma unroll
        for (int n = 0; n < 4; ++n) {
          float p = (zn + en_reg[kt * 4 + n]) - acc[m][n][r] * 0x1p-9f;
          if (p < rm1[q]) { rm2[q] = rm1[q]; rm1[q] = p; ri1[q] = c0i + n * 16; }
          else            { rm2[q] = fminf(rm2[q], p); }
        }
      }
    }
  }

  // one butterfly per row across the 16 lr-lanes
#pragma unroll
  for (int m = 0; m < 4; ++m) {
#pragma unroll
    for (int r = 0; r < 4; ++r) {
      int q = m * 4 + r;
      float m1 = rm1[q], m2 = rm2[q];
      int i1 = ri1[q];
#pragma unroll
      for (int msk = 1; msk <= 8; msk <<= 1) {
        float om1 = __shfl_xor(m1, msk);
        float om2 = __shfl_xor(m2, msk);
        int   oi1 = __shfl_xor(i1, msk);
        if (om1 < m1 || (om1 == m1 && oi1 < i1)) {
          m2 = fminf(m1, om2); m1 = om1; i1 = oi1;
        } else {
          m2 = fminf(m2, om1);
        }
      }
      if (lr == 0) {
        int pt = m * 16 + hq * 4 + r;
        rm1s[w][pt] = m1; rm2s[w][pt] = m2; ri1s[w][pt] = i1;
      }
    }
  }
  __syncthreads();

  if (tid < 64) {
    float m1 = rm1s[0][tid], m2 = rm2s[0][tid];
    int i1 = ri1s[0][tid];
#pragma unroll
    for (int pq = 1; pq < 4; ++pq) {
      float a1 = rm1s[pq][tid], a2 = rm2s[pq][tid];
      int ai = ri1s[pq][tid];
      if (a1 < m1 || (a1 == m1 && ai < i1)) {
        m2 = fminf(m1, a2); m1 = a1; i1 = ai;
      } else {
        m2 = fminf(m2, a1);
      }
    }
    int n = n0 + tid;
    out_idx[n] = (float)i1;
    if (m2 - m1 <= MARG) {
      int p = atomicAdd(flag_cnt, 1);
      if (p < NPTS) flags[p] = n;
    }
    double dv = (double)m1;
#pragma unroll
    for (int msk = 1; msk < 64; msk <<= 1) dv += __shfl_xor(dv, msk);
    if (tid == 0) atomicAdd(loss_acc, dv);
  }
}

// exact numpy-fp32-chain re-decision for flagged points
__global__ __launch_bounds__(256) void vq_recheck(
    const float* __restrict__ z, const float* __restrict__ emb,
    const float* __restrict__ enorm, const int* __restrict__ flag_cnt,
    const int* __restrict__ flags, float* __restrict__ out_idx) {
  __shared__ float zs[4][CH];
  __shared__ float znf[4];
  __shared__ float bm[256];
  __shared__ int   bi[256];
  int cnt = *flag_cnt; if (cnt > NPTS) cnt = NPTS;
  int t = threadIdx.x;
  for (int base = blockIdx.x * 4; base < cnt; base += gridDim.x * 4) {
#pragma unroll
    for (int q = 0; q < 4; ++q) {
      int ii = base + q; if (ii >= cnt) ii = cnt - 1;
      int n = flags[ii];
      int b = n / SPATIAL, s = n % SPATIAL;
      zs[q][t] = z[((size_t)b * CH + t) * SPATIAL + s];
    }
    __syncthreads();
    if (t < 4) {
      double sd = 0.0;
      for (int c = 0; c < CH; ++c) sd = fma((double)zs[t][c], (double)zs[t][c], sd);
      znf[t] = (float)sd;
    }
    __syncthreads();
    float best[4] = {1e30f, 1e30f, 1e30f, 1e30f};
    int besti[4] = {0, 0, 0, 0};
    for (int q = 0; q < 4; ++q) {
      int code = t + 256 * q;
      const float* er = emb + (size_t)code * CH;
      float g0 = 0.f, g1 = 0.f, g2 = 0.f, g3 = 0.f;
#pragma unroll 8
      for (int c = 0; c < CH; ++c) {
        float e = er[c];
        g0 = fmaf(zs[0][c], e, g0);
        g1 = fmaf(zs[1][c], e, g1);
        g2 = fmaf(zs[2][c], e, g2);
        g3 = fmaf(zs[3][c], e, g3);
      }
      float en = enorm[code];
      float d0 = (znf[0] + en) - 2.f * g0;
      float d1 = (znf[1] + en) - 2.f * g1;
      float d2 = (znf[2] + en) - 2.f * g2;
      float d3 = (znf[3] + en) - 2.f * g3;
      if (d0 < best[0]) { best[0] = d0; besti[0] = code; }
      if (d1 < best[1]) { best[1] = d1; besti[1] = code; }
      if (d2 < best[2]) { best[2] = d2; besti[2] = code; }
      if (d3 < best[3]) { best[3] = d3; besti[3] = code; }
    }
#pragma unroll
    for (int p = 0; p < 4; ++p) {
      bm[t] = best[p]; bi[t] = besti[p];
      __syncthreads();
      for (int off = 128; off > 0; off >>= 1) {
        if (t < off) {
          float ob = bm[t + off]; int oi = bi[t + off];
          if (ob < bm[t] || (ob == bm[t] && oi < bi[t])) { bm[t] = ob; bi[t] = oi; }
        }
        __syncthreads();
      }
      int ii = base + p;
      if (t == 0 && ii < cnt) out_idx[flags[ii]] = (float)bi[0];
      __syncthreads();
    }
  }
}

// 64-point blocks: gather each point's emb row ONCE (coalesced) into
// XOR-swizzled LDS, write out transposed coalesced. Also finalize loss.
__global__ __launch_bounds__(256) void vq_scatter(
    const float* __restrict__ emb, const float* __restrict__ out_idx,
    float* __restrict__ zq, const double* __restrict__ loss_acc,
    float* __restrict__ loss_out) {
  __shared__ float rows[64][256];   // rows[s][c ^ (s&31)]
  __shared__ int idxs[64];
  int tid = threadIdx.x;
  int n0 = blockIdx.x * 64;
  int b = n0 / SPATIAL, s0 = n0 % SPATIAL;
  if (tid < 64) idxs[tid] = (int)out_idx[n0 + tid];
  __syncthreads();
  int lane = tid & 63, grp = tid >> 6;
  for (int r = grp; r < 64; r += 4) {
    const float* er = emb + (size_t)idxs[r] * CH;
    int sw = r & 31;
#pragma unroll
    for (int i = 0; i < 4; ++i) {
      int c = lane + 64 * i;
      rows[r][c ^ sw] = er[c];
    }
  }
  __syncthreads();
  for (int it = 0; it < 64; ++it) {
    int c = grp * 64 + it;
    float v = rows[lane][c ^ (lane & 31)];
    zq[((size_t)(b * CH + c)) * SPATIAL + s0 + lane] = v;
  }
  if (blockIdx.x == 0 && tid == 0)
    loss_out[0] = (float)(loss_acc[0] * 1.25 / (double)ZQ_SIZE);
}

extern "C" void kernel_launch(void* const* d_in, const int* in_sizes, int n_in,
                              void* d_out, int out_size, void* d_ws, size_t ws_size,
                              hipStream_t stream) {
  const float* z   = (const float*)d_in[0];
  const float* emb = (const float*)d_in[1];
  float* out = (float*)d_out;
  char* ws = (char*)d_ws;

  double*   loss_acc = (double*)(ws + WS_LOSS);
  int*      flag_cnt = (int*)(ws + WS_CNT);
  float*    enorm    = (float*)(ws + WS_ENORM);
  _Float16* eh       = (_Float16*)(ws + WS_EH);
  _Float16* el       = (_Float16*)(ws + WS_EL);
  int*      flags    = (int*)(ws + WS_FLAGS);

  float* loss_out = out + ZQ_SIZE;
  float* out_idx  = out + ZQ_SIZE + 1;

  hipMemsetAsync(d_ws, 0, 16, stream);
  vq_prep<<<KCODES * CH / 256, 256, 0, stream>>>(emb, eh, el);
  vq_enorm<<<KCODES / 256, 256, 0, stream>>>(emb, enorm);
  vq_main<<<NPTS / 64, 256, 0, stream>>>(z, eh, el, enorm, out_idx,
                                         loss_acc, flag_cnt, flags);
  vq_recheck<<<512, 256, 0, stream>>>(z, emb, enorm, flag_cnt, flags, out_idx);
  vq_scatter<<<NPTS / 64, 256, 0, stream>>>(emb, out_idx, out, loss_acc, loss_out);
}

// Round 7
// 903.618 us; speedup vs baseline: 1.0411x; 1.0411x over previous
//
#include <hip/hip_runtime.h>

#define SPATIAL 32768
#define BATCH   4
#define CH      256
#define KCODES  1024
#define NPTS    (BATCH*SPATIAL)          // 131072
#define ZQ_SIZE (BATCH*CH*SPATIAL)       // 33554432

// workspace layout (bytes)
#define WS_LOSS  0                        // double
#define WS_CNT   8                        // int
#define WS_ENORM 16                       // float[1024]
#define WS_EH    4352                     // _Float16[1024*256] row-major
#define WS_EL    (WS_EH + KCODES*CH*2)
#define WS_FLAGS (WS_EL + KCODES*CH*2)    // int[NPTS]

#define MARG 1.5e-4f  // covers split err + MFMA-vs-chain diff + 2 ulp(512)

typedef _Float16 f16x8 __attribute__((ext_vector_type(8)));
typedef float    f32x4 __attribute__((ext_vector_type(4)));

// split e*1024 into f16 hi/lo, row-major (scattered 16B reads stay L2/L3-hot)
__global__ __launch_bounds__(256) void vq_prep(const float* __restrict__ emb,
                                               _Float16* __restrict__ eh,
                                               _Float16* __restrict__ el) {
  int i = blockIdx.x * 256 + threadIdx.x;
  float es = emb[i] * 1024.0f;
  _Float16 h = (_Float16)es;
  eh[i] = h;
  el[i] = (_Float16)(es - (float)h);
}

__global__ __launch_bounds__(256) void vq_enorm(const float* __restrict__ emb,
                                                float* __restrict__ enorm) {
  int k = blockIdx.x * 256 + threadIdx.x;
  const float* e = emb + (size_t)k * CH;
  double s = 0.0;
#pragma unroll 8
  for (int c = 0; c < CH; ++c) s = fma((double)e[c], (double)e[c], s);
  enorm[k] = (float)s;
}

// 2048 blocks x 256 thr; block = 64 points x all 1024 codes, f16-split MFMA.
// A-fragments from conflict-free zfrag LDS (r5 layout, measured 0 conflicts);
// B-fragments double-buffered in regs from ROW-MAJOR e (r4 layout, L2-hot).
// n=2 tile per wave per kt: acc[4][2] -> no spill (r5: 128 VGPR, clean).
__global__ __launch_bounds__(256, 2) void vq_main(
    const float* __restrict__ z, const _Float16* __restrict__ eh_g,
    const _Float16* __restrict__ el_g, const float* __restrict__ enorm,
    float* __restrict__ out_idx, double* __restrict__ loss_acc,
    int* __restrict__ flag_cnt, int* __restrict__ flags) {
  __shared__ f16x8 zfrag[64][64];   // [h*32 + m*8 + cc][lane]  = 64 KB
  __shared__ double znp[4][64];
  __shared__ float  znb[64];
  __shared__ float rm1s[4][64];
  __shared__ float rm2s[4][64];
  __shared__ int   ri1s[4][64];

  int tid = threadIdx.x;
  int w = tid >> 6;
  int lane = tid & 63;
  int n0 = blockIdx.x * 64;
  int b = n0 / SPATIAL, s0 = n0 % SPATIAL;
  const float* zb = z + (size_t)b * CH * SPATIAL + s0;

  // stage z as f16 hi/lo directly into fragment order; f64 zn partials
  {
    int pt = lane, m = pt >> 4, lr = pt & 15;
    const float* zcol = zb + pt;
    double zacc = 0.0;
#pragma unroll
    for (int oct = 0; oct < 8; ++oct) {
      int c0 = w * 64 + oct * 8;
      int cc = c0 >> 5, hq = (c0 >> 3) & 3;
      f16x8 h8, l8;
#pragma unroll
      for (int i = 0; i < 8; ++i) {
        float v = zcol[(size_t)(c0 + i) * SPATIAL];
        zacc = fma((double)v, (double)v, zacc);
        _Float16 hh = (_Float16)v;
        h8[i] = hh;
        l8[i] = (_Float16)(v - (float)hh);
      }
      zfrag[m * 8 + cc][hq * 16 + lr] = h8;
      zfrag[32 + m * 8 + cc][hq * 16 + lr] = l8;
    }
    znp[w][pt] = zacc;
  }
  __syncthreads();
  if (tid < 64)
    znb[tid] = (float)(znp[0][tid] + znp[1][tid] + znp[2][tid] + znp[3][tid]);
  __syncthreads();

  int hq = lane >> 4;
  int lr = lane & 15;

  // enorm in registers: [kt*2 + n]
  float en_reg[16];
#pragma unroll
  for (int kt = 0; kt < 8; ++kt) {
    en_reg[kt * 2]     = enorm[kt * 128 + w * 32 + lr];
    en_reg[kt * 2 + 1] = enorm[kt * 128 + w * 32 + lr + 16];
  }
  float znr[16];
#pragma unroll
  for (int m = 0; m < 4; ++m)
#pragma unroll
    for (int r = 0; r < 4; ++r) znr[m * 4 + r] = znb[m * 16 + hq * 4 + r];

  float rm1[16], rm2[16];
  int   ri1[16];
#pragma unroll
  for (int q = 0; q < 16; ++q) { rm1[q] = 1e30f; rm2[q] = 1e30f; ri1[q] = 0; }

  // row-major e bases for this wave's code rows (lr-th row of each subtile)
  const _Float16* ehb = eh_g + (size_t)(w * 32 + lr) * CH;
  const _Float16* elb = el_g + (size_t)(w * 32 + lr) * CH;

  for (int kt = 0; kt < 8; ++kt) {
    size_t ko = (size_t)kt * 128 * CH;
    f32x4 acc[4][2];
#pragma unroll
    for (int m = 0; m < 4; ++m)
#pragma unroll
      for (int n = 0; n < 2; ++n) acc[m][n] = (f32x4){0.f, 0.f, 0.f, 0.f};

    // double-buffered B-fragments: prefetch cc+1 while MFMAing cc
    f16x8 bh[2][2], bl[2][2];
    {
      int ca = hq * 8;
      bh[0][0] = *(const f16x8*)&ehb[ko + ca];
      bh[0][1] = *(const f16x8*)&ehb[ko + (size_t)16 * CH + ca];
      bl[0][0] = *(const f16x8*)&elb[ko + ca];
      bl[0][1] = *(const f16x8*)&elb[ko + (size_t)16 * CH + ca];
    }
#pragma unroll
    for (int cc = 0; cc < 8; ++cc) {
      int cur = cc & 1, nxt = cur ^ 1;
      if (cc < 7) {
        int ca = (cc + 1) * 32 + hq * 8;
        bh[nxt][0] = *(const f16x8*)&ehb[ko + ca];
        bh[nxt][1] = *(const f16x8*)&ehb[ko + (size_t)16 * CH + ca];
        bl[nxt][0] = *(const f16x8*)&elb[ko + ca];
        bl[nxt][1] = *(const f16x8*)&elb[ko + (size_t)16 * CH + ca];
      }
      f16x8 ah[4], al[4];
#pragma unroll
      for (int m = 0; m < 4; ++m) {
        ah[m] = zfrag[m * 8 + cc][lane];
        al[m] = zfrag[32 + m * 8 + cc][lane];
      }
#pragma unroll
      for (int m = 0; m < 4; ++m)
#pragma unroll
        for (int n = 0; n < 2; ++n) {
          acc[m][n] = __builtin_amdgcn_mfma_f32_16x16x32_f16(ah[m], bh[cur][n], acc[m][n], 0, 0, 0);
          acc[m][n] = __builtin_amdgcn_mfma_f32_16x16x32_f16(al[m], bh[cur][n], acc[m][n], 0, 0, 0);
          acc[m][n] = __builtin_amdgcn_mfma_f32_16x16x32_f16(ah[m], bl[cur][n], acc[m][n], 0, 0, 0);
        }
    }

    // fold into per-thread top-2 (D-frag: row = hq*4+r, col = lr)
    float enA = en_reg[kt * 2], enB = en_reg[kt * 2 + 1];
    int c0i = kt * 128 + w * 32 + lr;
#pragma unroll
    for (int m = 0; m < 4; ++m) {
#pragma unroll
      for (int r = 0; r < 4; ++r) {
        int q = m * 4 + r;
        float zn = znr[q];
        float p0 = (zn + enA) - acc[m][0][r] * 0x1p-9f;
        float p1 = (zn + enB) - acc[m][1][r] * 0x1p-9f;
        if (p0 < rm1[q]) { rm2[q] = rm1[q]; rm1[q] = p0; ri1[q] = c0i; }
        else             { rm2[q] = fminf(rm2[q], p0); }
        if (p1 < rm1[q]) { rm2[q] = rm1[q]; rm1[q] = p1; ri1[q] = c0i + 16; }
        else             { rm2[q] = fminf(rm2[q], p1); }
      }
    }
  }

  // one butterfly per row across the 16 lr-lanes
#pragma unroll
  for (int m = 0; m < 4; ++m) {
#pragma unroll
    for (int r = 0; r < 4; ++r) {
      int q = m * 4 + r;
      float m1 = rm1[q], m2 = rm2[q];
      int i1 = ri1[q];
#pragma unroll
      for (int msk = 1; msk <= 8; msk <<= 1) {
        float om1 = __shfl_xor(m1, msk);
        float om2 = __shfl_xor(m2, msk);
        int   oi1 = __shfl_xor(i1, msk);
        if (om1 < m1 || (om1 == m1 && oi1 < i1)) {
          m2 = fminf(m1, om2); m1 = om1; i1 = oi1;
        } else {
          m2 = fminf(m2, om1);
        }
      }
      if (lr == 0) {
        int pt = m * 16 + hq * 4 + r;
        rm1s[w][pt] = m1; rm2s[w][pt] = m2; ri1s[w][pt] = i1;
      }
    }
  }
  __syncthreads();

  if (tid < 64) {
    float m1 = rm1s[0][tid], m2 = rm2s[0][tid];
    int i1 = ri1s[0][tid];
#pragma unroll
    for (int pq = 1; pq < 4; ++pq) {
      float a1 = rm1s[pq][tid], a2 = rm2s[pq][tid];
      int ai = ri1s[pq][tid];
      if (a1 < m1 || (a1 == m1 && ai < i1)) {
        m2 = fminf(m1, a2); m1 = a1; i1 = ai;
      } else {
        m2 = fminf(m2, a1);
      }
    }
    int n = n0 + tid;
    out_idx[n] = (float)i1;
    if (m2 - m1 <= MARG) {
      int p = atomicAdd(flag_cnt, 1);
      if (p < NPTS) flags[p] = n;
    }
    double dv = (double)m1;
#pragma unroll
    for (int msk = 1; msk < 64; msk <<= 1) dv += __shfl_xor(dv, msk);
    if (tid == 0) atomicAdd(loss_acc, dv);
  }
}

// exact numpy-fp32-chain re-decision for flagged points
__global__ __launch_bounds__(256) void vq_recheck(
    const float* __restrict__ z, const float* __restrict__ emb,
    const float* __restrict__ enorm, const int* __restrict__ flag_cnt,
    const int* __restrict__ flags, float* __restrict__ out_idx) {
  __shared__ float zs[4][CH];
  __shared__ float znf[4];
  __shared__ float bm[256];
  __shared__ int   bi[256];
  int cnt = *flag_cnt; if (cnt > NPTS) cnt = NPTS;
  int t = threadIdx.x;
  for (int base = blockIdx.x * 4; base < cnt; base += gridDim.x * 4) {
#pragma unroll
    for (int q = 0; q < 4; ++q) {
      int ii = base + q; if (ii >= cnt) ii = cnt - 1;
      int n = flags[ii];
      int b = n / SPATIAL, s = n % SPATIAL;
      zs[q][t] = z[((size_t)b * CH + t) * SPATIAL + s];
    }
    __syncthreads();
    if (t < 4) {
      double sd = 0.0;
      for (int c = 0; c < CH; ++c) sd = fma((double)zs[t][c], (double)zs[t][c], sd);
      znf[t] = (float)sd;
    }
    __syncthreads();
    float best[4] = {1e30f, 1e30f, 1e30f, 1e30f};
    int besti[4] = {0, 0, 0, 0};
    for (int q = 0; q < 4; ++q) {
      int code = t + 256 * q;
      const float* er = emb + (size_t)code * CH;
      float g0 = 0.f, g1 = 0.f, g2 = 0.f, g3 = 0.f;
#pragma unroll 8
      for (int c = 0; c < CH; ++c) {
        float e = er[c];
        g0 = fmaf(zs[0][c], e, g0);
        g1 = fmaf(zs[1][c], e, g1);
        g2 = fmaf(zs[2][c], e, g2);
        g3 = fmaf(zs[3][c], e, g3);
      }
      float en = enorm[code];
      float d0 = (znf[0] + en) - 2.f * g0;
      float d1 = (znf[1] + en) - 2.f * g1;
      float d2 = (znf[2] + en) - 2.f * g2;
      float d3 = (znf[3] + en) - 2.f * g3;
      if (d0 < best[0]) { best[0] = d0; besti[0] = code; }
      if (d1 < best[1]) { best[1] = d1; besti[1] = code; }
      if (d2 < best[2]) { best[2] = d2; besti[2] = code; }
      if (d3 < best[3]) { best[3] = d3; besti[3] = code; }
    }
#pragma unroll
    for (int p = 0; p < 4; ++p) {
      bm[t] = best[p]; bi[t] = besti[p];
      __syncthreads();
      for (int off = 128; off > 0; off >>= 1) {
        if (t < off) {
          float ob = bm[t + off]; int oi = bi[t + off];
          if (ob < bm[t] || (ob == bm[t] && oi < bi[t])) { bm[t] = ob; bi[t] = oi; }
        }
        __syncthreads();
      }
      int ii = base + p;
      if (t == 0 && ii < cnt) out_idx[flags[ii]] = (float)bi[0];
      __syncthreads();
    }
  }
}

// 64-point blocks: gather each point's emb row ONCE (coalesced) into
// XOR-swizzled LDS, write out transposed coalesced. Also finalize loss.
__global__ __launch_bounds__(256) void vq_scatter(
    const float* __restrict__ emb, const float* __restrict__ out_idx,
    float* __restrict__ zq, const double* __restrict__ loss_acc,
    float* __restrict__ loss_out) {
  __shared__ float rows[64][256];   // rows[s][c ^ (s&31)]
  __shared__ int idxs[64];
  int tid = threadIdx.x;
  int n0 = blockIdx.x * 64;
  int b = n0 / SPATIAL, s0 = n0 % SPATIAL;
  if (tid < 64) idxs[tid] = (int)out_idx[n0 + tid];
  __syncthreads();
  int lane = tid & 63, grp = tid >> 6;
  for (int r = grp; r < 64; r += 4) {
    const float* er = emb + (size_t)idxs[r] * CH;
    int sw = r & 31;
#pragma unroll
    for (int i = 0; i < 4; ++i) {
      int c = lane + 64 * i;
      rows[r][c ^ sw] = er[c];
    }
  }
  __syncthreads();
  for (int it = 0; it < 64; ++it) {
    int c = grp * 64 + it;
    float v = rows[lane][c ^ (lane & 31)];
    zq[((size_t)(b * CH + c)) * SPATIAL + s0 + lane] = v;
  }
  if (blockIdx.x == 0 && tid == 0)
    loss_out[0] = (float)(loss_acc[0] * 1.25 / (double)ZQ_SIZE);
}

extern "C" void kernel_launch(void* const* d_in, const int* in_sizes, int n_in,
                              void* d_out, int out_size, void* d_ws, size_t ws_size,
                              hipStream_t stream) {
  const float* z   = (const float*)d_in[0];
  const float* emb = (const float*)d_in[1];
  float* out = (float*)d_out;
  char* ws = (char*)d_ws;

  double*   loss_acc = (double*)(ws + WS_LOSS);
  int*      flag_cnt = (int*)(ws + WS_CNT);
  float*    enorm    = (float*)(ws + WS_ENORM);
  _Float16* eh       = (_Float16*)(ws + WS_EH);
  _Float16* el       = (_Float16*)(ws + WS_EL);
  int*      flags    = (int*)(ws + WS_FLAGS);

  float* loss_out = out + ZQ_SIZE;
  float* out_idx  = out + ZQ_SIZE + 1;

  hipMemsetAsync(d_ws, 0, 16, stream);
  vq_prep<<<KCODES * CH / 256, 256, 0, stream>>>(emb, eh, el);
  vq_enorm<<<KCODES / 256, 256, 0, stream>>>(emb, enorm);
  vq_main<<<NPTS / 64, 256, 0, stream>>>(z, eh, el, enorm, out_idx,
                                         loss_acc, flag_cnt, flags);
  vq_recheck<<<512, 256, 0, stream>>>(z, emb, enorm, flag_cnt, flags, out_idx);
  vq_scatter<<<NPTS / 64, 256, 0, stream>>>(emb, out_idx, out, loss_acc, loss_out);
}

// Round 8
// 732.161 us; speedup vs baseline: 1.2849x; 1.2342x over previous
//
#include <hip/hip_runtime.h>

#define SPATIAL 32768
#define BATCH   4
#define CH      256
#define KCODES  1024
#define NPTS    (BATCH*SPATIAL)          // 131072
#define ZQ_SIZE (BATCH*CH*SPATIAL)       // 33554432

// workspace layout (bytes)
#define WS_LOSS  0                        // double
#define WS_CNT   8                        // int
#define WS_ENORM 16                       // float[1024]
#define WS_EH    4352                     // _Float16[1024*256] row-major
#define WS_EL    (WS_EH + KCODES*CH*2)
#define WS_FLAGS (WS_EL + KCODES*CH*2)    // int[NPTS]

#define MARG 1.5e-4f  // covers split err + MFMA-vs-chain diff + 2 ulp(512)

typedef _Float16 f16x8 __attribute__((ext_vector_type(8)));
typedef float    f32x4 __attribute__((ext_vector_type(4)));

// split e*1024 into f16 hi/lo, row-major
__global__ __launch_bounds__(256) void vq_prep(const float* __restrict__ emb,
                                               _Float16* __restrict__ eh,
                                               _Float16* __restrict__ el) {
  int i = blockIdx.x * 256 + threadIdx.x;
  float es = emb[i] * 1024.0f;
  _Float16 h = (_Float16)es;
  eh[i] = h;
  el[i] = (_Float16)(es - (float)h);
}

__global__ __launch_bounds__(256) void vq_enorm(const float* __restrict__ emb,
                                                float* __restrict__ enorm) {
  int k = blockIdx.x * 256 + threadIdx.x;
  const float* e = emb + (size_t)k * CH;
  double s = 0.0;
#pragma unroll 8
  for (int c = 0; c < CH; ++c) s = fma((double)e[c], (double)e[c], s);
  enorm[k] = (float)s;
}

// 4096 blocks x 256 thr; block = 32 points x all 1024 codes, f16-split MFMA.
// Small per-thread state (no spill): acc[2][2]+rm[8] ~90 VGPR; 4 blocks/CU.
__global__ __launch_bounds__(256) void vq_main(
    const float* __restrict__ z, const _Float16* __restrict__ eh_g,
    const _Float16* __restrict__ el_g, const float* __restrict__ enorm,
    float* __restrict__ out_idx, double* __restrict__ loss_acc,
    int* __restrict__ flag_cnt, int* __restrict__ flags) {
  __shared__ f16x8 zfrag[32][64];   // rows: hi m*8+cc, lo 16+m*8+cc; col lane
  __shared__ double znp[8][32];
  __shared__ float  znb[32];
  __shared__ float rm1s[4][32];
  __shared__ float rm2s[4][32];
  __shared__ int   ri1s[4][32];

  int tid = threadIdx.x;
  int w = tid >> 6;
  int lane = tid & 63;
  int n0 = blockIdx.x * 32;
  int b = n0 / SPATIAL, s0 = n0 % SPATIAL;
  const float* zb = z + (size_t)b * CH * SPATIAL + s0;

  // stage z as f16 hi/lo in fragment order; thread covers 32 ch of one point
  {
    int pt = tid & 31, cg = tid >> 5;       // cg = cc chunk 0..7
    int m = pt >> 4, lr = pt & 15;
    const float* zcol = zb + pt;
    double zacc = 0.0;
#pragma unroll
    for (int hq = 0; hq < 4; ++hq) {
      int c0 = cg * 32 + hq * 8;
      f16x8 h8, l8;
#pragma unroll
      for (int i = 0; i < 8; ++i) {
        float v = zcol[(size_t)(c0 + i) * SPATIAL];
        zacc = fma((double)v, (double)v, zacc);
        _Float16 hh = (_Float16)v;
        h8[i] = hh;
        l8[i] = (_Float16)(v - (float)hh);
      }
      zfrag[m * 8 + cg][hq * 16 + lr] = h8;
      zfrag[16 + m * 8 + cg][hq * 16 + lr] = l8;
    }
    znp[cg][pt] = zacc;
  }
  __syncthreads();
  if (tid < 32) {
    double s = 0.0;
#pragma unroll
    for (int g = 0; g < 8; ++g) s += znp[g][tid];
    znb[tid] = (float)s;
  }
  __syncthreads();

  int hq = lane >> 4;
  int lr = lane & 15;

  float znr[8];
#pragma unroll
  for (int m = 0; m < 2; ++m)
#pragma unroll
    for (int r = 0; r < 4; ++r) znr[m * 4 + r] = znb[m * 16 + hq * 4 + r];

  float rm1[8], rm2[8];
  int   ri1[8];
#pragma unroll
  for (int q = 0; q < 8; ++q) { rm1[q] = 1e30f; rm2[q] = 1e30f; ri1[q] = 0; }

  // row-major e bases: wave covers codes kt*128 + w*32 + {lr, 16+lr}
  const _Float16* ehb = eh_g + (size_t)(w * 32 + lr) * CH;
  const _Float16* elb = el_g + (size_t)(w * 32 + lr) * CH;

  for (int kt = 0; kt < 8; ++kt) {
    size_t ko = (size_t)kt * 128 * CH;
    f32x4 acc[2][2];
#pragma unroll
    for (int m = 0; m < 2; ++m)
#pragma unroll
      for (int n = 0; n < 2; ++n) acc[m][n] = (f32x4){0.f, 0.f, 0.f, 0.f};

#pragma unroll
    for (int cc = 0; cc < 8; ++cc) {
      int ca = cc * 32 + hq * 8;
      f16x8 ah[2], al[2], bh[2], bl[2];
      bh[0] = *(const f16x8*)&ehb[ko + ca];
      bh[1] = *(const f16x8*)&ehb[ko + (size_t)16 * CH + ca];
      bl[0] = *(const f16x8*)&elb[ko + ca];
      bl[1] = *(const f16x8*)&elb[ko + (size_t)16 * CH + ca];
#pragma unroll
      for (int m = 0; m < 2; ++m) {
        ah[m] = zfrag[m * 8 + cc][lane];
        al[m] = zfrag[16 + m * 8 + cc][lane];
      }
#pragma unroll
      for (int m = 0; m < 2; ++m)
#pragma unroll
        for (int n = 0; n < 2; ++n) {
          acc[m][n] = __builtin_amdgcn_mfma_f32_16x16x32_f16(ah[m], bh[n], acc[m][n], 0, 0, 0);
          acc[m][n] = __builtin_amdgcn_mfma_f32_16x16x32_f16(al[m], bh[n], acc[m][n], 0, 0, 0);
          acc[m][n] = __builtin_amdgcn_mfma_f32_16x16x32_f16(ah[m], bl[n], acc[m][n], 0, 0, 0);
        }
    }

    // fold into per-thread top-2 (D-frag: row = hq*4+r, col = lr)
    float enA = enorm[kt * 128 + w * 32 + lr];
    float enB = enorm[kt * 128 + w * 32 + 16 + lr];
    int c0i = kt * 128 + w * 32 + lr;
#pragma unroll
    for (int m = 0; m < 2; ++m) {
#pragma unroll
      for (int r = 0; r < 4; ++r) {
        int q = m * 4 + r;
        float zn = znr[q];
        float p0 = (zn + enA) - acc[m][0][r] * 0x1p-9f;
        float p1 = (zn + enB) - acc[m][1][r] * 0x1p-9f;
        if (p0 < rm1[q]) { rm2[q] = rm1[q]; rm1[q] = p0; ri1[q] = c0i; }
        else             { rm2[q] = fminf(rm2[q], p0); }
        if (p1 < rm1[q]) { rm2[q] = rm1[q]; rm1[q] = p1; ri1[q] = c0i + 16; }
        else             { rm2[q] = fminf(rm2[q], p1); }
      }
    }
  }

  // one butterfly per row across the 16 lr-lanes
#pragma unroll
  for (int m = 0; m < 2; ++m) {
#pragma unroll
    for (int r = 0; r < 4; ++r) {
      int q = m * 4 + r;
      float m1 = rm1[q], m2 = rm2[q];
      int i1 = ri1[q];
#pragma unroll
      for (int msk = 1; msk <= 8; msk <<= 1) {
        float om1 = __shfl_xor(m1, msk);
        float om2 = __shfl_xor(m2, msk);
        int   oi1 = __shfl_xor(i1, msk);
        if (om1 < m1 || (om1 == m1 && oi1 < i1)) {
          m2 = fminf(m1, om2); m1 = om1; i1 = oi1;
        } else {
          m2 = fminf(m2, om1);
        }
      }
      if (lr == 0) {
        int pt = m * 16 + hq * 4 + r;
        rm1s[w][pt] = m1; rm2s[w][pt] = m2; ri1s[w][pt] = i1;
      }
    }
  }
  __syncthreads();

  if (tid < 32) {
    float m1 = rm1s[0][tid], m2 = rm2s[0][tid];
    int i1 = ri1s[0][tid];
#pragma unroll
    for (int pq = 1; pq < 4; ++pq) {
      float a1 = rm1s[pq][tid], a2 = rm2s[pq][tid];
      int ai = ri1s[pq][tid];
      if (a1 < m1 || (a1 == m1 && ai < i1)) {
        m2 = fminf(m1, a2); m1 = a1; i1 = ai;
      } else {
        m2 = fminf(m2, a1);
      }
    }
    int n = n0 + tid;
    out_idx[n] = (float)i1;
    if (m2 - m1 <= MARG) {
      int p = atomicAdd(flag_cnt, 1);
      if (p < NPTS) flags[p] = n;
    }
    double dv = (double)m1;
#pragma unroll
    for (int msk = 1; msk < 32; msk <<= 1) dv += __shfl_xor(dv, msk);
    if (tid == 0) atomicAdd(loss_acc, dv);
  }
}

// exact numpy-fp32-chain re-decision for flagged points
__global__ __launch_bounds__(256) void vq_recheck(
    const float* __restrict__ z, const float* __restrict__ emb,
    const float* __restrict__ enorm, const int* __restrict__ flag_cnt,
    const int* __restrict__ flags, float* __restrict__ out_idx) {
  __shared__ float zs[4][CH];
  __shared__ float znf[4];
  __shared__ float bm[256];
  __shared__ int   bi[256];
  int cnt = *flag_cnt; if (cnt > NPTS) cnt = NPTS;
  int t = threadIdx.x;
  for (int base = blockIdx.x * 4; base < cnt; base += gridDim.x * 4) {
#pragma unroll
    for (int q = 0; q < 4; ++q) {
      int ii = base + q; if (ii >= cnt) ii = cnt - 1;
      int n = flags[ii];
      int b = n / SPATIAL, s = n % SPATIAL;
      zs[q][t] = z[((size_t)b * CH + t) * SPATIAL + s];
    }
    __syncthreads();
    if (t < 4) {
      double sd = 0.0;
      for (int c = 0; c < CH; ++c) sd = fma((double)zs[t][c], (double)zs[t][c], sd);
      znf[t] = (float)sd;
    }
    __syncthreads();
    float best[4] = {1e30f, 1e30f, 1e30f, 1e30f};
    int besti[4] = {0, 0, 0, 0};
    for (int q = 0; q < 4; ++q) {
      int code = t + 256 * q;
      const float* er = emb + (size_t)code * CH;
      float g0 = 0.f, g1 = 0.f, g2 = 0.f, g3 = 0.f;
#pragma unroll 8
      for (int c = 0; c < CH; ++c) {
        float e = er[c];
        g0 = fmaf(zs[0][c], e, g0);
        g1 = fmaf(zs[1][c], e, g1);
        g2 = fmaf(zs[2][c], e, g2);
        g3 = fmaf(zs[3][c], e, g3);
      }
      float en = enorm[code];
      float d0 = (znf[0] + en) - 2.f * g0;
      float d1 = (znf[1] + en) - 2.f * g1;
      float d2 = (znf[2] + en) - 2.f * g2;
      float d3 = (znf[3] + en) - 2.f * g3;
      if (d0 < best[0]) { best[0] = d0; besti[0] = code; }
      if (d1 < best[1]) { best[1] = d1; besti[1] = code; }
      if (d2 < best[2]) { best[2] = d2; besti[2] = code; }
      if (d3 < best[3]) { best[3] = d3; besti[3] = code; }
    }
#pragma unroll
    for (int p = 0; p < 4; ++p) {
      bm[t] = best[p]; bi[t] = besti[p];
      __syncthreads();
      for (int off = 128; off > 0; off >>= 1) {
        if (t < off) {
          float ob = bm[t + off]; int oi = bi[t + off];
          if (ob < bm[t] || (ob == bm[t] && oi < bi[t])) { bm[t] = ob; bi[t] = oi; }
        }
        __syncthreads();
      }
      int ii = base + p;
      if (t == 0 && ii < cnt) out_idx[flags[ii]] = (float)bi[0];
      __syncthreads();
    }
  }
}

// 64-point blocks: gather each point's emb row ONCE into XOR-swizzled LDS,
// write transposed coalesced. Also finalize loss.
__global__ __launch_bounds__(256) void vq_scatter(
    const float* __restrict__ emb, const float* __restrict__ out_idx,
    float* __restrict__ zq, const double* __restrict__ loss_acc,
    float* __restrict__ loss_out) {
  __shared__ float rows[64][256];   // rows[s][c ^ (s&31)]
  __shared__ int idxs[64];
  int tid = threadIdx.x;
  int n0 = blockIdx.x * 64;
  int b = n0 / SPATIAL, s0 = n0 % SPATIAL;
  if (tid < 64) idxs[tid] = (int)out_idx[n0 + tid];
  __syncthreads();
  int lane = tid & 63, grp = tid >> 6;
  for (int r = grp; r < 64; r += 4) {
    const float* er = emb + (size_t)idxs[r] * CH;
    int sw = r & 31;
#pragma unroll
    for (int i = 0; i < 4; ++i) {
      int c = lane + 64 * i;
      rows[r][c ^ sw] = er[c];
    }
  }
  __syncthreads();
  for (int it = 0; it < 64; ++it) {
    int c = grp * 64 + it;
    float v = rows[lane][c ^ (lane & 31)];
    zq[((size_t)(b * CH + c)) * SPATIAL + s0 + lane] = v;
  }
  if (blockIdx.x == 0 && tid == 0)
    loss_out[0] = (float)(loss_acc[0] * 1.25 / (double)ZQ_SIZE);
}

extern "C" void kernel_launch(void* const* d_in, const int* in_sizes, int n_in,
                              void* d_out, int out_size, void* d_ws, size_t ws_size,
                              hipStream_t stream) {
  const float* z   = (const float*)d_in[0];
  const float* emb = (const float*)d_in[1];
  float* out = (float*)d_out;
  char* ws = (char*)d_ws;

  double*   loss_acc = (double*)(ws + WS_LOSS);
  int*      flag_cnt = (int*)(ws + WS_CNT);
  float*    enorm    = (float*)(ws + WS_ENORM);
  _Float16* eh       = (_Float16*)(ws + WS_EH);
  _Float16* el       = (_Float16*)(ws + WS_EL);
  int*      flags    = (int*)(ws + WS_FLAGS);

  float* loss_out = out + ZQ_SIZE;
  float* out_idx  = out + ZQ_SIZE + 1;

  hipMemsetAsync(d_ws, 0, 16, stream);
  vq_prep<<<KCODES * CH / 256, 256, 0, stream>>>(emb, eh, el);
  vq_enorm<<<KCODES / 256, 256, 0, stream>>>(emb, enorm);
  vq_main<<<NPTS / 32, 256, 0, stream>>>(z, eh, el, enorm, out_idx,
                                         loss_acc, flag_cnt, flags);
  vq_recheck<<<512, 256, 0, stream>>>(z, emb, enorm, flag_cnt, flags, out_idx);
  vq_scatter<<<NPTS / 64, 256, 0, stream>>>(emb, out_idx, out, loss_acc, loss_out);
}